// Round 1
// baseline (203.091 us; speedup 1.0000x reference)
//
#include <hip/hip_runtime.h>

// GraphUnetPool: scores = sigmoid(h@w+b); top-k (k=N/2) by exact rank-count;
// new_h = h[idx]*values; un_g = (g@g)[idx][:,idx] via sparse 2-path counting.

typedef unsigned long long u64;
typedef unsigned int u32;

// ---- scores: one wave per row, dot(h[row], w) over D=256 via float4 ----
__global__ void scores_kernel(const float* __restrict__ h, const float* __restrict__ w,
                              const float* __restrict__ b, u64* __restrict__ keys, int N) {
    int wave = (blockIdx.x * blockDim.x + threadIdx.x) >> 6;
    int lane = threadIdx.x & 63;
    if (wave >= N) return;
    const float4 a = ((const float4*)(h + (size_t)wave * 256))[lane];
    const float4 c = ((const float4*)w)[lane];
    float s = a.x * c.x + a.y * c.y + a.z * c.z + a.w * c.w;
    #pragma unroll
    for (int off = 32; off; off >>= 1) s += __shfl_xor(s, off);
    if (lane == 0) {
        s += b[0];
        float sc = 1.0f / (1.0f + expf(-s));
        u32 sb = __float_as_uint(sc);                       // sc in (0,1): bits monotonic
        keys[wave] = ((u64)sb << 32) | (u32)(~wave);        // ties -> lower index first
    }
}

// ---- exact rank = #{j: key_j > key_i}; tile keys through LDS (broadcast reads) ----
__global__ void rank_count_kernel(const u64* __restrict__ keys, int* __restrict__ rankcnt, int N) {
    __shared__ u64 lk[1024];
    int ngroups = N >> 8;                       // element groups of 256
    int elg = blockIdx.x % ngroups;
    int chunk = blockIdx.x / ngroups;           // key chunks of 1024
    int base = chunk << 10;
    for (int i = threadIdx.x; i < 1024; i += 256) lk[i] = keys[base + i];
    __syncthreads();
    int el = (elg << 8) + threadIdx.x;
    u64 mk = keys[el];
    int cnt = 0;
    #pragma unroll 8
    for (int i = 0; i < 1024; ++i) cnt += (lk[i] > mk) ? 1 : 0;
    atomicAdd(&rankcnt[el], cnt);
}

// ---- scatter by rank: build idx/value lists, rank LUT, write idx & batch outputs ----
__global__ void select_kernel(const u64* __restrict__ keys, const int* __restrict__ rankcnt,
                              const int* __restrict__ batch, int* __restrict__ idx_list,
                              float* __restrict__ val_list, int* __restrict__ rank,
                              float* __restrict__ out_idx, float* __restrict__ out_batch,
                              int N, int kN) {
    int i = blockIdx.x * blockDim.x + threadIdx.x;
    if (i >= N) return;
    int r = rankcnt[i];
    rank[i] = (r < kN) ? r : -1;
    if (r < kN) {
        idx_list[r] = i;
        val_list[r] = __uint_as_float((u32)(keys[i] >> 32));
        out_idx[r] = (float)i;
        out_batch[r] = (float)batch[i];
    }
}

// ---- new_h = h[idx] * values (one wave per row, float4) ----
__global__ void newh_kernel(const float* __restrict__ h, const int* __restrict__ idx_list,
                            const float* __restrict__ val_list, float* __restrict__ out, int kN) {
    int wave = (blockIdx.x * blockDim.x + threadIdx.x) >> 6;
    int lane = threadIdx.x & 63;
    if (wave >= kN) return;
    int i = idx_list[wave];
    float v = val_list[wave];
    float4 a = ((const float4*)(h + (size_t)i * 256))[lane];
    ((float4*)(out + (size_t)wave * 256))[lane] = make_float4(a.x * v, a.y * v, a.z * v, a.w * v);
}

__global__ void ones_kernel(float4* __restrict__ out, int n4) {
    int i = blockIdx.x * blockDim.x + threadIdx.x;
    int stride = gridDim.x * blockDim.x;
    float4 one = make_float4(1.f, 1.f, 1.f, 1.f);
    for (; i < n4; i += stride) out[i] = one;
}

// ---- CSR build: out-degree histogram, exclusive scan, neighbor scatter ----
__global__ void hist_kernel(const int* __restrict__ ei0, int* __restrict__ deg, int E) {
    int e = blockIdx.x * blockDim.x + threadIdx.x;
    if (e < E) atomicAdd(&deg[ei0[e]], 1);
}

__global__ void scan_kernel(const int* __restrict__ deg, int* __restrict__ offs,
                            int* __restrict__ cursor, int N) {
    // N == 8192, 1024 threads, 8 per thread
    __shared__ int part[1024];
    int t = threadIdx.x;
    int base = t * 8;
    int loc[8];
    int s = 0;
    #pragma unroll
    for (int j = 0; j < 8; ++j) { loc[j] = s; s += deg[base + j]; }
    part[t] = s;
    __syncthreads();
    for (int d = 1; d < 1024; d <<= 1) {
        int v = (t >= d) ? part[t - d] : 0;
        __syncthreads();
        part[t] += v;
        __syncthreads();
    }
    int excl = (t == 0) ? 0 : part[t - 1];
    #pragma unroll
    for (int j = 0; j < 8; ++j) { int o = excl + loc[j]; offs[base + j] = o; cursor[base + j] = o; }
    if (t == 1023) offs[N] = part[1023];
}

__global__ void scatter_kernel(const int* __restrict__ ei0, const int* __restrict__ ei1,
                               int* __restrict__ cursor, int* __restrict__ nbr, int E) {
    int e = blockIdx.x * blockDim.x + threadIdx.x;
    if (e < E) {
        int p = atomicAdd(&cursor[ei0[e]], 1);
        nbr[p] = ei1[e];
    }
}

// ---- 2-path accumulation: edge (u->v) is first hop; fan out over v's out-edges ----
__global__ void paths_kernel(const int* __restrict__ ei0, const int* __restrict__ ei1,
                             const int* __restrict__ offs, const int* __restrict__ nbr,
                             const int* __restrict__ rank, float* __restrict__ ung,
                             int E, int kN) {
    int e = blockIdx.x * blockDim.x + threadIdx.x;
    if (e >= E) return;
    int u = ei0[e];
    int ru = rank[u];
    if (ru < 0) return;
    int v = ei1[e];
    int s = offs[v], t = offs[v + 1];
    float* row = ung + (size_t)ru * kN;
    for (int p = s; p < t; ++p) {
        int rw = rank[nbr[p]];
        if (rw >= 0) atomicAdd(&row[rw], 1.0f);
    }
}

extern "C" void kernel_launch(void* const* d_in, const int* in_sizes, int n_in,
                              void* d_out, int out_size, void* d_ws, size_t ws_size,
                              hipStream_t stream) {
    const float* h = (const float*)d_in[0];
    const int* ei = (const int*)d_in[1];            // [2,E] flat: ei0 = ei, ei1 = ei+E
    const int* batch = (const int*)d_in[3];
    const float* pw = (const float*)d_in[4];
    const float* pb = (const float*)d_in[5];

    int N = in_sizes[3];        // 8192
    int E = in_sizes[1] / 2;    // 262144
    int kN = N / 2;
    if (kN < 2) kN = 2;

    float* out = (float*)d_out;
    float* out_newh = out;                              // kN*256
    float* out_ung = out_newh + (size_t)kN * 256;       // kN*kN
    float* out_ea = out_ung + (size_t)kN * kN;          // E
    float* out_nb = out_ea + E;                         // kN
    float* out_idx = out_nb + kN;                       // kN

    char* ws = (char*)d_ws;
    u64* keys    = (u64*)(ws + 0);          // 64 KB
    int* rankcnt = (int*)(ws + 65536);      // 32 KB
    int* idx_list= (int*)(ws + 98304);      // 16 KB
    float* vals  = (float*)(ws + 114688);   // 16 KB
    int* rank    = (int*)(ws + 131072);     // 32 KB
    int* deg     = (int*)(ws + 163840);     // 32 KB
    int* offs    = (int*)(ws + 196608);     // 32 KB + 4
    int* cursor  = (int*)(ws + 229632);     // 32 KB
    int* nbr     = (int*)(ws + 262400);     // 1 MB

    hipMemsetAsync(rankcnt, 0, (size_t)N * 4, stream);
    hipMemsetAsync(deg, 0, (size_t)N * 4, stream);
    hipMemsetAsync(out_ung, 0, (size_t)kN * kN * 4, stream);

    scores_kernel<<<N / 4, 256, 0, stream>>>(h, pw, pb, keys, N);
    rank_count_kernel<<<(N / 256) * (N / 1024), 256, 0, stream>>>(keys, rankcnt, N);
    select_kernel<<<N / 256, 256, 0, stream>>>(keys, rankcnt, batch, idx_list, vals, rank,
                                               out_idx, out_nb, N, kN);
    newh_kernel<<<kN / 4, 256, 0, stream>>>(h, idx_list, vals, out_newh, kN);
    ones_kernel<<<256, 256, 0, stream>>>((float4*)out_ea, E / 4);

    hist_kernel<<<E / 256, 256, 0, stream>>>(ei, deg, E);
    scan_kernel<<<1, 1024, 0, stream>>>(deg, offs, cursor, N);
    scatter_kernel<<<E / 256, 256, 0, stream>>>(ei, ei + E, cursor, nbr, E);
    paths_kernel<<<E / 256, 256, 0, stream>>>(ei, ei + E, offs, nbr, rank, out_ung, E, kN);
}

// Round 2
// 111.507 us; speedup vs baseline: 1.8213x; 1.8213x over previous
//
#include <hip/hip_runtime.h>

// GraphUnetPool: scores = sigmoid(h@w+b); top-k (k=N/2) by exact rank-count;
// new_h = h[idx]*values; un_g = (g@g)[idx][:,idx] via per-row LDS 2-path counting.

typedef unsigned long long u64;
typedef unsigned int u32;

// ---- scores: one wave per row, dot(h[row], w) over D=256 via float4 ----
__global__ void scores_kernel(const float* __restrict__ h, const float* __restrict__ w,
                              const float* __restrict__ b, u64* __restrict__ keys, int N) {
    int wave = (blockIdx.x * blockDim.x + threadIdx.x) >> 6;
    int lane = threadIdx.x & 63;
    if (wave >= N) return;
    const float4 a = ((const float4*)(h + (size_t)wave * 256))[lane];
    const float4 c = ((const float4*)w)[lane];
    float s = a.x * c.x + a.y * c.y + a.z * c.z + a.w * c.w;
    #pragma unroll
    for (int off = 32; off; off >>= 1) s += __shfl_xor(s, off);
    if (lane == 0) {
        s += b[0];
        float sc = 1.0f / (1.0f + expf(-s));
        u32 sb = __float_as_uint(sc);                       // sc in (0,1): bits monotonic
        keys[wave] = ((u64)sb << 32) | (u32)(~wave);        // ties -> lower index first
    }
}

// ---- exact rank = #{j: key_j > key_i}; tile keys through LDS (broadcast reads) ----
__global__ void rank_count_kernel(const u64* __restrict__ keys, int* __restrict__ rankcnt, int N) {
    __shared__ u64 lk[1024];
    int ngroups = N >> 8;                       // element groups of 256
    int elg = blockIdx.x % ngroups;
    int chunk = blockIdx.x / ngroups;           // key chunks of 1024
    int base = chunk << 10;
    for (int i = threadIdx.x; i < 1024; i += 256) lk[i] = keys[base + i];
    __syncthreads();
    int el = (elg << 8) + threadIdx.x;
    u64 mk = keys[el];
    int cnt = 0;
    #pragma unroll 8
    for (int i = 0; i < 1024; ++i) cnt += (lk[i] > mk) ? 1 : 0;
    atomicAdd(&rankcnt[el], cnt);
}

// ---- scatter by rank: idx/value lists, rank LUT (kN = discard slot), outputs ----
__global__ void select_kernel(const u64* __restrict__ keys, const int* __restrict__ rankcnt,
                              const int* __restrict__ batch, int* __restrict__ idx_list,
                              float* __restrict__ val_list, int* __restrict__ rank,
                              float* __restrict__ out_idx, float* __restrict__ out_batch,
                              int N, int kN) {
    int i = blockIdx.x * blockDim.x + threadIdx.x;
    if (i >= N) return;
    int r = rankcnt[i];
    rank[i] = (r < kN) ? r : kN;               // kN == discard slot
    if (r < kN) {
        idx_list[r] = i;
        val_list[r] = __uint_as_float((u32)(keys[i] >> 32));
        out_idx[r] = (float)i;
        out_batch[r] = (float)batch[i];
    }
}

// ---- new_h = h[idx] * values (one wave per row, float4) ----
__global__ void newh_kernel(const float* __restrict__ h, const int* __restrict__ idx_list,
                            const float* __restrict__ val_list, float* __restrict__ out, int kN) {
    int wave = (blockIdx.x * blockDim.x + threadIdx.x) >> 6;
    int lane = threadIdx.x & 63;
    if (wave >= kN) return;
    int i = idx_list[wave];
    float v = val_list[wave];
    float4 a = ((const float4*)(h + (size_t)i * 256))[lane];
    ((float4*)(out + (size_t)wave * 256))[lane] = make_float4(a.x * v, a.y * v, a.z * v, a.w * v);
}

__global__ void ones_kernel(float4* __restrict__ out, int n4) {
    int i = blockIdx.x * blockDim.x + threadIdx.x;
    int stride = gridDim.x * blockDim.x;
    float4 one = make_float4(1.f, 1.f, 1.f, 1.f);
    for (; i < n4; i += stride) out[i] = one;
}

// ---- CSR build: out-degree histogram, exclusive scan, neighbor scatter ----
__global__ void hist_kernel(const int* __restrict__ ei0, int* __restrict__ deg, int E) {
    int e = blockIdx.x * blockDim.x + threadIdx.x;
    if (e < E) atomicAdd(&deg[ei0[e]], 1);
}

__global__ void scan_kernel(const int* __restrict__ deg, int* __restrict__ offs,
                            int* __restrict__ cursor, int N) {
    // N == 8192, 1024 threads, 8 per thread
    __shared__ int part[1024];
    int t = threadIdx.x;
    int base = t * 8;
    int loc[8];
    int s = 0;
    #pragma unroll
    for (int j = 0; j < 8; ++j) { loc[j] = s; s += deg[base + j]; }
    part[t] = s;
    __syncthreads();
    for (int d = 1; d < 1024; d <<= 1) {
        int v = (t >= d) ? part[t - d] : 0;
        __syncthreads();
        part[t] += v;
        __syncthreads();
    }
    int excl = (t == 0) ? 0 : part[t - 1];
    #pragma unroll
    for (int j = 0; j < 8; ++j) { int o = excl + loc[j]; offs[base + j] = o; cursor[base + j] = o; }
    if (t == 1023) offs[N] = part[1023];
}

__global__ void scatter_kernel(const int* __restrict__ ei0, const int* __restrict__ ei1,
                               int* __restrict__ cursor, int* __restrict__ nbr, int E) {
    int e = blockIdx.x * blockDim.x + threadIdx.x;
    if (e < E) {
        int p = atomicAdd(&cursor[ei0[e]], 1);
        nbr[p] = ei1[e];
    }
}

// ---- 2-path accumulation: one block per output row; LDS row accumulator ----
__global__ void paths_row_kernel(const int* __restrict__ idx_list, const int* __restrict__ offs,
                                 const int* __restrict__ nbr, const int* __restrict__ rank,
                                 float* __restrict__ ung, int kN) {
    extern __shared__ float row[];              // kN+1 floats; row[kN] = discard
    int tid = threadIdx.x;
    for (int i = tid; i < kN + 1; i += 256) row[i] = 0.f;
    __syncthreads();
    int u = idx_list[blockIdx.x];
    int s0 = offs[u], s1 = offs[u + 1];
    int wid = tid >> 6, lane = tid & 63;
    for (int p = s0 + wid; p < s1; p += 4) {    // wave per first-hop edge
        int v = nbr[p];
        int t0 = offs[v], t1 = offs[v + 1];
        for (int q = t0 + lane; q < t1; q += 64)
            atomicAdd(&row[rank[nbr[q]]], 1.0f);
    }
    __syncthreads();
    float4* dst = (float4*)(ung + (size_t)blockIdx.x * kN);
    const float4* src = (const float4*)row;
    for (int i = tid; i < (kN >> 2); i += 256) dst[i] = src[i];
}

extern "C" void kernel_launch(void* const* d_in, const int* in_sizes, int n_in,
                              void* d_out, int out_size, void* d_ws, size_t ws_size,
                              hipStream_t stream) {
    const float* h = (const float*)d_in[0];
    const int* ei = (const int*)d_in[1];            // [2,E] flat: ei0 = ei, ei1 = ei+E
    const int* batch = (const int*)d_in[3];
    const float* pw = (const float*)d_in[4];
    const float* pb = (const float*)d_in[5];

    int N = in_sizes[3];        // 8192
    int E = in_sizes[1] / 2;    // 262144
    int kN = N / 2;
    if (kN < 2) kN = 2;

    float* out = (float*)d_out;
    float* out_newh = out;                              // kN*256
    float* out_ung = out_newh + (size_t)kN * 256;       // kN*kN
    float* out_ea = out_ung + (size_t)kN * kN;          // E
    float* out_nb = out_ea + E;                         // kN
    float* out_idx = out_nb + kN;                       // kN

    char* ws = (char*)d_ws;
    u64* keys    = (u64*)(ws + 0);          // 64 KB
    int* rankcnt = (int*)(ws + 65536);      // 32 KB \ single memset covers
    int* deg     = (int*)(ws + 98304);      // 32 KB / both (64 KB)
    int* idx_list= (int*)(ws + 131072);     // 16 KB
    float* vals  = (float*)(ws + 147456);   // 16 KB
    int* rank    = (int*)(ws + 163840);     // 32 KB
    int* offs    = (int*)(ws + 196608);     // 32 KB + 4
    int* cursor  = (int*)(ws + 229632);     // 32 KB
    int* nbr     = (int*)(ws + 262400);     // 1 MB

    hipMemsetAsync(rankcnt, 0, 2 * (size_t)N * 4, stream);   // rankcnt + deg

    scores_kernel<<<N / 4, 256, 0, stream>>>(h, pw, pb, keys, N);
    rank_count_kernel<<<(N / 256) * (N / 1024), 256, 0, stream>>>(keys, rankcnt, N);
    select_kernel<<<N / 256, 256, 0, stream>>>(keys, rankcnt, batch, idx_list, vals, rank,
                                               out_idx, out_nb, N, kN);
    newh_kernel<<<kN / 4, 256, 0, stream>>>(h, idx_list, vals, out_newh, kN);
    ones_kernel<<<256, 256, 0, stream>>>((float4*)out_ea, E / 4);

    hist_kernel<<<E / 256, 256, 0, stream>>>(ei, deg, E);
    scan_kernel<<<1, 1024, 0, stream>>>(deg, offs, cursor, N);
    scatter_kernel<<<E / 256, 256, 0, stream>>>(ei, ei + E, cursor, nbr, E);
    paths_row_kernel<<<kN, 256, (kN + 1) * 4, stream>>>(idx_list, offs, nbr, rank, out_ung, kN);
}

// Round 3
// 107.765 us; speedup vs baseline: 1.8846x; 1.0347x over previous
//
#include <hip/hip_runtime.h>

// GraphUnetPool: scores = sigmoid(h@w+b); top-k (k=N/2) by exact rank-count;
// new_h = h[idx]*values; un_g = (g@g)[idx][:,idx] via per-row LDS 2-path counting.

typedef unsigned long long u64;
typedef unsigned int u32;

// ---- scores: one wave per row, dot(h[row], w) over D=256 via float4 ----
// Also zeroes rankcnt+deg (2*N ints) so no hipMemsetAsync dispatch is needed.
__global__ void scores_kernel(const float* __restrict__ h, const float* __restrict__ w,
                              const float* __restrict__ b, u64* __restrict__ keys,
                              int* __restrict__ zerobuf, int N) {
    int g = blockIdx.x * blockDim.x + threadIdx.x;
    if (g < 2 * N) zerobuf[g] = 0;              // rankcnt (N) + deg (N), adjacent
    int wave = g >> 6;
    int lane = threadIdx.x & 63;
    if (wave >= N) return;
    const float4 a = ((const float4*)(h + (size_t)wave * 256))[lane];
    const float4 c = ((const float4*)w)[lane];
    float s = a.x * c.x + a.y * c.y + a.z * c.z + a.w * c.w;
    #pragma unroll
    for (int off = 32; off; off >>= 1) s += __shfl_xor(s, off);
    if (lane == 0) {
        s += b[0];
        float sc = 1.0f / (1.0f + expf(-s));
        u32 sb = __float_as_uint(sc);                       // sc in (0,1): bits monotonic
        keys[wave] = ((u64)sb << 32) | (u32)(~wave);        // ties -> lower index first
    }
}

// ---- exact rank = #{j: key_j > key_i}; tile keys through LDS (broadcast reads) ----
__global__ void rank_count_kernel(const u64* __restrict__ keys, int* __restrict__ rankcnt, int N) {
    __shared__ u64 lk[1024];
    int ngroups = N >> 8;                       // element groups of 256
    int elg = blockIdx.x % ngroups;
    int chunk = blockIdx.x / ngroups;           // key chunks of 1024
    int base = chunk << 10;
    for (int i = threadIdx.x; i < 1024; i += 256) lk[i] = keys[base + i];
    __syncthreads();
    int el = (elg << 8) + threadIdx.x;
    u64 mk = keys[el];
    int cnt = 0;
    #pragma unroll 8
    for (int i = 0; i < 1024; ++i) cnt += (lk[i] > mk) ? 1 : 0;
    atomicAdd(&rankcnt[el], cnt);
}

// ---- scatter by rank: idx/value lists, rank LUT (kN = discard slot), outputs ----
__global__ void select_kernel(const u64* __restrict__ keys, const int* __restrict__ rankcnt,
                              const int* __restrict__ batch, int* __restrict__ idx_list,
                              float* __restrict__ val_list, int* __restrict__ rank,
                              float* __restrict__ out_idx, float* __restrict__ out_batch,
                              int N, int kN) {
    int i = blockIdx.x * blockDim.x + threadIdx.x;
    if (i >= N) return;
    int r = rankcnt[i];
    rank[i] = (r < kN) ? r : kN;               // kN == discard slot
    if (r < kN) {
        idx_list[r] = i;
        val_list[r] = __uint_as_float((u32)(keys[i] >> 32));
        out_idx[r] = (float)i;
        out_batch[r] = (float)batch[i];
    }
}

// ---- new_h = h[idx] * values (one wave per row, float4) ----
__global__ void newh_kernel(const float* __restrict__ h, const int* __restrict__ idx_list,
                            const float* __restrict__ val_list, float* __restrict__ out, int kN) {
    int wave = (blockIdx.x * blockDim.x + threadIdx.x) >> 6;
    int lane = threadIdx.x & 63;
    if (wave >= kN) return;
    int i = idx_list[wave];
    float v = val_list[wave];
    float4 a = ((const float4*)(h + (size_t)i * 256))[lane];
    ((float4*)(out + (size_t)wave * 256))[lane] = make_float4(a.x * v, a.y * v, a.z * v, a.w * v);
}

__global__ void ones_kernel(float4* __restrict__ out, int n4) {
    int i = blockIdx.x * blockDim.x + threadIdx.x;
    int stride = gridDim.x * blockDim.x;
    float4 one = make_float4(1.f, 1.f, 1.f, 1.f);
    for (; i < n4; i += stride) out[i] = one;
}

// ---- CSR build: out-degree histogram, exclusive scan, neighbor scatter ----
__global__ void hist_kernel(const int* __restrict__ ei0, int* __restrict__ deg, int E) {
    int e = blockIdx.x * blockDim.x + threadIdx.x;
    if (e < E) atomicAdd(&deg[ei0[e]], 1);
}

__global__ void scan_kernel(const int* __restrict__ deg, int* __restrict__ offs,
                            int* __restrict__ cursor, int N) {
    // N == 8192, 1024 threads, 8 per thread
    __shared__ int part[1024];
    int t = threadIdx.x;
    int base = t * 8;
    int loc[8];
    int s = 0;
    #pragma unroll
    for (int j = 0; j < 8; ++j) { loc[j] = s; s += deg[base + j]; }
    part[t] = s;
    __syncthreads();
    for (int d = 1; d < 1024; d <<= 1) {
        int v = (t >= d) ? part[t - d] : 0;
        __syncthreads();
        part[t] += v;
        __syncthreads();
    }
    int excl = (t == 0) ? 0 : part[t - 1];
    #pragma unroll
    for (int j = 0; j < 8; ++j) { int o = excl + loc[j]; offs[base + j] = o; cursor[base + j] = o; }
    if (t == 1023) offs[N] = part[1023];
}

__global__ void scatter_kernel(const int* __restrict__ ei0, const int* __restrict__ ei1,
                               int* __restrict__ cursor, int* __restrict__ nbr, int E) {
    int e = blockIdx.x * blockDim.x + threadIdx.x;
    if (e < E) {
        int p = atomicAdd(&cursor[ei0[e]], 1);
        nbr[p] = ei1[e];
    }
}

// ---- 2-path accumulation: one block per output row; LDS row accumulator ----
__global__ void paths_row_kernel(const int* __restrict__ idx_list, const int* __restrict__ offs,
                                 const int* __restrict__ nbr, const int* __restrict__ rank,
                                 float* __restrict__ ung, int kN) {
    extern __shared__ float row[];              // kN+1 floats; row[kN] = discard
    int tid = threadIdx.x;
    for (int i = tid; i < kN + 1; i += 256) row[i] = 0.f;
    __syncthreads();
    int u = idx_list[blockIdx.x];
    int s0 = offs[u], s1 = offs[u + 1];
    int wid = tid >> 6, lane = tid & 63;
    for (int p = s0 + wid; p < s1; p += 4) {    // wave per first-hop edge
        int v = nbr[p];
        int t0 = offs[v], t1 = offs[v + 1];
        for (int q = t0 + lane; q < t1; q += 64)
            atomicAdd(&row[rank[nbr[q]]], 1.0f);
    }
    __syncthreads();
    float4* dst = (float4*)(ung + (size_t)blockIdx.x * kN);
    const float4* src = (const float4*)row;
    for (int i = tid; i < (kN >> 2); i += 256) dst[i] = src[i];
}

extern "C" void kernel_launch(void* const* d_in, const int* in_sizes, int n_in,
                              void* d_out, int out_size, void* d_ws, size_t ws_size,
                              hipStream_t stream) {
    const float* h = (const float*)d_in[0];
    const int* ei = (const int*)d_in[1];            // [2,E] flat: ei0 = ei, ei1 = ei+E
    const int* batch = (const int*)d_in[3];
    const float* pw = (const float*)d_in[4];
    const float* pb = (const float*)d_in[5];

    int N = in_sizes[3];        // 8192
    int E = in_sizes[1] / 2;    // 262144
    int kN = N / 2;
    if (kN < 2) kN = 2;

    float* out = (float*)d_out;
    float* out_newh = out;                              // kN*256
    float* out_ung = out_newh + (size_t)kN * 256;       // kN*kN
    float* out_ea = out_ung + (size_t)kN * kN;          // E
    float* out_nb = out_ea + E;                         // kN
    float* out_idx = out_nb + kN;                       // kN

    char* ws = (char*)d_ws;
    u64* keys    = (u64*)(ws + 0);          // 64 KB
    int* rankcnt = (int*)(ws + 65536);      // 32 KB \ zeroed together in
    int* deg     = (int*)(ws + 98304);      // 32 KB / scores_kernel
    int* idx_list= (int*)(ws + 131072);     // 16 KB
    float* vals  = (float*)(ws + 147456);   // 16 KB
    int* rank    = (int*)(ws + 163840);     // 32 KB
    int* offs    = (int*)(ws + 196608);     // 32 KB + 4
    int* cursor  = (int*)(ws + 229632);     // 32 KB
    int* nbr     = (int*)(ws + 262400);     // 1 MB

    scores_kernel<<<N / 4, 256, 0, stream>>>(h, pw, pb, keys, rankcnt, N);
    rank_count_kernel<<<(N / 256) * (N / 1024), 256, 0, stream>>>(keys, rankcnt, N);
    select_kernel<<<N / 256, 256, 0, stream>>>(keys, rankcnt, batch, idx_list, vals, rank,
                                               out_idx, out_nb, N, kN);
    newh_kernel<<<kN / 4, 256, 0, stream>>>(h, idx_list, vals, out_newh, kN);
    ones_kernel<<<256, 256, 0, stream>>>((float4*)out_ea, E / 4);

    hist_kernel<<<E / 256, 256, 0, stream>>>(ei, deg, E);
    scan_kernel<<<1, 1024, 0, stream>>>(deg, offs, cursor, N);
    scatter_kernel<<<E / 256, 256, 0, stream>>>(ei, ei + E, cursor, nbr, E);
    paths_row_kernel<<<kN, 256, (kN + 1) * 4, stream>>>(idx_list, offs, nbr, rank, out_ung, kN);
}